// Round 14
// baseline (27.655 us; speedup 1.0000x reference)
//
#include <hip/hip_runtime.h>

#define Bn 1024
#define Pn 128
#define Fn 512
#define Dn 256
#define THETA 1e-7f
#define F16_MINN 6.103515625e-5f   // smallest normal f16

typedef _Float16 f16;
typedef f16 f16x8 __attribute__((ext_vector_type(8)));
typedef f16 f16x4 __attribute__((ext_vector_type(4)));
typedef f16 f16x2 __attribute__((ext_vector_type(2)));
typedef float f32x4 __attribute__((ext_vector_type(4)));

#if defined(__has_builtin)
#if __has_builtin(__builtin_amdgcn_fdot2)
#define FDOT2(a, b, c) __builtin_amdgcn_fdot2((a), (b), (c), false)
#endif
#endif
#ifndef FDOT2
#define FDOT2(a, b, c) ((float)(a)[0] * (float)(b)[0] + (float)(a)[1] * (float)(b)[1] + (c))
#endif

__device__ __forceinline__ f16x2 get2(const f16x8 v, int idx) {
    union { f16x8 v8; f16x2 v2[4]; } u;
    u.v8 = v;
    return u.v2[idx];
}

// ---------------------------------------------------------------------------
// K1: exact f32 GEMM [x; prototypes] @ fb^T (round-1 body, proven).
// Epilogue emits f16 relu values with positives CLAMPED to f16 min-normal:
//   stored > 0  <=>  exact f32 v > 0   (masks reconstructible in K2)
//   rows <  Bn: RX[b][F]          row-major f16
//   rows >= Bn: RPT8 [F/8][P][8]  8-f groups per p contiguous
// (mask arrays deleted -> half the epilogue stores of round 13)
// ---------------------------------------------------------------------------
__global__ __launch_bounds__(256)
void gemm_feat(const float* __restrict__ x, const float* __restrict__ prot,
               const float* __restrict__ fb,
               f16* __restrict__ RX, f16* __restrict__ RPT8)
{
    __shared__ float As[64][68];
    __shared__ float Fs[64][68];
    const int tid = threadIdx.x;
    const int rb  = blockIdx.y * 64;
    const int cb  = blockIdx.x * 64;
    const int tx  = tid & 15;
    const int ty  = tid >> 4;
    const int lr  = tid >> 2;
    const int lk  = tid & 3;

    float acc[4][4] = {};

    for (int k0 = 0; k0 < Dn; k0 += 64) {
        #pragma unroll
        for (int q = 0; q < 4; ++q) {
            const int kk = lk + q * 4;
            const int r  = rb + lr;
            const float* asrc = (r < Bn) ? (x + (size_t)r * Dn)
                                         : (prot + (size_t)(r - Bn) * Dn);
            float4 av = *(const float4*)(asrc + k0 + kk * 4);
            float4 fv = *(const float4*)(fb + (size_t)(cb + lr) * Dn + k0 + kk * 4);
            As[kk*4+0][lr] = av.x; As[kk*4+1][lr] = av.y;
            As[kk*4+2][lr] = av.z; As[kk*4+3][lr] = av.w;
            Fs[kk*4+0][lr] = fv.x; Fs[kk*4+1][lr] = fv.y;
            Fs[kk*4+2][lr] = fv.z; Fs[kk*4+3][lr] = fv.w;
        }
        __syncthreads();
        #pragma unroll 8
        for (int k = 0; k < 64; ++k) {
            float4 a = *(const float4*)&As[k][ty * 4];
            float4 f = *(const float4*)&Fs[k][tx * 4];
            const float aa[4] = {a.x, a.y, a.z, a.w};
            const float ff[4] = {f.x, f.y, f.z, f.w};
            #pragma unroll
            for (int i = 0; i < 4; ++i)
                #pragma unroll
                for (int j = 0; j < 4; ++j)
                    acc[i][j] = fmaf(aa[i], ff[j], acc[i][j]);
        }
        __syncthreads();
    }

    const f16 MINN = (f16)F16_MINN;
    #pragma unroll
    for (int i = 0; i < 4; ++i) {
        const int r = rb + ty * 4 + i;
        if (r < Bn) {
            f16x4 rv;
            #pragma unroll
            for (int j = 0; j < 4; ++j) {
                const float v = acc[i][j];
                f16 t = (f16)0;
                if (v > 0.f) { t = (f16)v; if (t < MINN) t = MINN; }
                rv[j] = t;
            }
            *(f16x4*)(RX + (size_t)r * Fn + cb + tx * 4) = rv;
        } else {
            const int p = r - Bn;
            #pragma unroll
            for (int j = 0; j < 4; ++j) {
                const int c = cb + tx * 4 + j;
                const float v = acc[i][j];
                f16 t = (f16)0;
                if (v > 0.f) { t = (f16)v; if (t < MINN) t = MINN; }
                RPT8[(size_t)(c >> 3) * (Pn * 8) + p * 8 + (c & 7)] = t;
            }
        }
    }
}

// ---------------------------------------------------------------------------
// K2 v5: 4b x 4p register tile, NO mask loads.
//  bx/bp reconstructed exactly in-register: b = min(r * 65504, 1)
//  (r is 0 or >= f16 min-normal 6.1e-5 -> product saturates >=3.99 or inf -> 1).
//  Loads per 8f group: 4 rx8 + 4 rp8 = 128 B for 128 output-f -> 1 B/of,
//  67 MB total issued (was 201 MB) => ~1.7 us at 64 B/cyc/CU L1 ceiling.
//  Block = 16b x 16p tile; 16 threads-tiles (4x4) x 16 F-slices (32 f) = 256.
//  Grid (Bn/16, Pn/16) = 64 x 8 = 512 blocks, 64 KB LDS -> 2 blocks/CU.
//  Deterministic LDS slice-reduce; 256 threads write ratios.
// ---------------------------------------------------------------------------
__global__ __launch_bounds__(256)
void tversky_main(const f16* __restrict__ RX, const f16* __restrict__ RPT8,
                  const float* __restrict__ alpha_p, const float* __restrict__ beta_p,
                  float* __restrict__ out)
{
    __shared__ f32x4 sAcc[16][256];          // [slice][local b*16+p] = {I,M,X,P}
    const int tid   = threadIdx.x;
    const int ot    = tid & 15;              // output tile 0..15
    const int slice = tid >> 4;              // F-slice 0..15
    const int bt    = ot >> 2;               // 0..3
    const int pt    = ot & 3;                // 0..3
    const int bb    = blockIdx.x * 16;
    const int pb    = blockIdx.y * 16;
    const int b0    = bb + bt * 4;
    const int p0    = pb + pt * 4;
    const int g0    = slice * 4;             // first f16x8 group of this slice

    float aI[4][4] = {};
    float aM[4][4] = {};
    float aX[4][4] = {};
    float aP[4][4] = {};

    const f16x2 one2 = {(f16)1, (f16)1};
    f16x8 KS, ONE8;
    #pragma unroll
    for (int e = 0; e < 8; ++e) { KS[e] = (f16)65504.0f; ONE8[e] = (f16)1; }

    #pragma unroll
    for (int g = 0; g < 4; ++g) {            // 4 groups of 8 f = 32 f
        const size_t xoff = (size_t)(g0 + g) * 8;
        f16x8 rx[4], bx[4];
        #pragma unroll
        for (int i = 0; i < 4; ++i) {
            rx[i] = *(const f16x8*)(RX + (size_t)(b0 + i) * Fn + xoff);
            bx[i] = __builtin_elementwise_min(rx[i] * KS, ONE8);
        }
        const size_t pbase = (size_t)(g0 + g) * (Pn * 8) + (size_t)p0 * 8;
        f16x8 rp[4], bp[4];
        #pragma unroll
        for (int q = 0; q < 4; ++q) {
            rp[q] = *(const f16x8*)(RPT8 + pbase + q * 8);
            bp[q] = __builtin_elementwise_min(rp[q] * KS, ONE8);
        }
        #pragma unroll
        for (int i = 0; i < 4; ++i) {
            #pragma unroll
            for (int q = 0; q < 4; ++q) {
                const f16x8 mn = __builtin_elementwise_min(rx[i], rp[q]);
                #pragma unroll
                for (int h = 0; h < 4; ++h) {
                    aI[i][q] = FDOT2(get2(rx[i], h), get2(rp[q], h), aI[i][q]);
                    aM[i][q] = FDOT2(get2(mn, h),    one2,           aM[i][q]);
                    aX[i][q] = FDOT2(get2(rx[i], h), get2(bp[q], h), aX[i][q]);
                    aP[i][q] = FDOT2(get2(bx[i], h), get2(rp[q], h), aP[i][q]);
                }
            }
        }
    }

    #pragma unroll
    for (int i = 0; i < 4; ++i) {
        #pragma unroll
        for (int q = 0; q < 4; ++q) {
            const int outIdx = (bt * 4 + i) * 16 + pt * 4 + q;
            f32x4 v = {aI[i][q], aM[i][q], aX[i][q], aP[i][q]};
            sAcc[slice][outIdx] = v;
        }
    }
    __syncthreads();

    {
        f32x4 acc = sAcc[0][tid];
        #pragma unroll
        for (int s = 1; s < 16; ++s) acc += sAcc[s][tid];
        const float alpha = *alpha_p;
        const float beta  = *beta_p;
        const float I = acc[0], M = acc[1], X = acc[2], P = acc[3];
        const float W = alpha * (X - M) + beta * (P - M);
        const int brow = tid >> 4, pcol = tid & 15;
        out[(size_t)(bb + brow) * Pn + pb + pcol] = I / (I + W + THETA);
    }
}

extern "C" void kernel_launch(void* const* d_in, const int* in_sizes, int n_in,
                              void* d_out, int out_size, void* d_ws, size_t ws_size,
                              hipStream_t stream)
{
    const float* x     = (const float*)d_in[0];
    const float* prot  = (const float*)d_in[1];
    const float* fb    = (const float*)d_in[2];
    const float* alpha = (const float*)d_in[3];
    const float* beta  = (const float*)d_in[4];
    float* out = (float*)d_out;

    f16* RX   = (f16*)d_ws;                   // Bn*Fn f16
    f16* RPT8 = RX + (size_t)Bn * Fn;         // Fn*Pn f16  ([F/8][P][8])

    dim3 gg(Fn / 64, (Bn + Pn) / 64);         // 8 x 18 = 144 blocks
    gemm_feat<<<gg, 256, 0, stream>>>(x, prot, fb, RX, RPT8);

    dim3 gm(Bn / 16, Pn / 16);                // 64 x 8 = 512 blocks
    tversky_main<<<gm, 256, 0, stream>>>(RX, RPT8, alpha, beta, out);
}